// Round 19
// baseline (40.956 us; speedup 1.0000x reference)
//
#include <hip/hip_runtime.h>

// PairwiseRankLoss: U=262144 users x G=64 items, K=2, MARGIN=0.3
// R19 = R18 asm-load pipeline, race fixed:
//  R18 failed because the register-rotation copies (cta=nta) read asm-load
//  destination registers while the loads were still in flight (compiler
//  no longer tracks opaque asm loads; only s_waitcnt protects reads).
//  Fix: FULL UNROLL with two named register sets (A/B), strict double
//  buffering -- loads for body b+1 target the set not being computed; a
//  set is read only after its counted s_waitcnt vmcnt(6)+sched_barrier.
// Compute: R17 8-lanes/user x 8-items/lane all-DPP signed-space bitonic,
// index-embedded selection keys, LDS y_hat gather. Two-stage reduce.

static constexpr int kUsers = 262144;
static constexpr int kBlock = 256;                  // 4 waves / block
static constexpr int kGrid  = 2048;
static constexpr int kWavesPerBlock = kBlock / 64;
static constexpr int kTotalWaves = kGrid * kWavesPerBlock;   // 8192
static constexpr int kUsersPerWave = kUsers / kTotalWaves;   // 32
static constexpr float kMargin = 0.3f;

template<int CTRL>
static __device__ __forceinline__ float movdppf(float x) {
    return __uint_as_float((unsigned)__builtin_amdgcn_mov_dpp(
        (int)__float_as_uint(x), CTRL, 0xF, 0xF, false));
}
template<int CTRL>
static __device__ __forceinline__ unsigned movdppu(unsigned x) {
    return (unsigned)__builtin_amdgcn_mov_dpp((int)x, CTRL, 0xF, 0xF, false);
}
static __device__ __forceinline__ float xorf(float x, unsigned m) {
    return __uint_as_float(__float_as_uint(x) ^ m);
}
static __device__ __forceinline__ float cnd(float mx, float mn,
                                            unsigned long long keep) {
    float d;
    asm("v_cndmask_b32 %0, %1, %2, %3" : "=v"(d) : "v"(mx), "v"(mn), "s"(keep));
    return d;
}
template<int CTRL>
static __device__ __forceinline__ float cexd(float w, unsigned long long keep) {
    const float p = movdppf<CTRL>(w);
    return cnd(fmaxf(w, p), fminf(w, p), keep);
}
static __device__ __forceinline__ unsigned umax_(unsigned a, unsigned b){ return a>b?a:b; }
static __device__ __forceinline__ unsigned umin_(unsigned a, unsigned b){ return a<b?a:b; }

// un-sinkable, un-rematerializable 16B load (manual vmcnt discipline!)
static __device__ __forceinline__ float4 gload4(const float* p) {
    float4 r;
    asm volatile("global_load_dwordx4 %0, %1, off" : "=v"(r) : "v"(p));
    return r;
}

#define CE2A(a, b) { float mn_=fminf(a,b), mx_=fmaxf(a,b); (a)=mn_; (b)=mx_; }
#define CE2D(a, b) { float mn_=fminf(a,b), mx_=fmaxf(a,b); (a)=mx_; (b)=mn_; }
#define FLIPALL(m) { w0=xorf(w0,m); w1=xorf(w1,m); w2=xorf(w2,m); w3=xorf(w3,m); \
                     w4=xorf(w4,m); w5=xorf(w5,m); w6=xorf(w6,m); w7=xorf(w7,m); }
#define CEXALL(CTRL, keep) { w0=cexd<CTRL>(w0,keep); w1=cexd<CTRL>(w1,keep); \
                             w2=cexd<CTRL>(w2,keep); w3=cexd<CTRL>(w3,keep); \
                             w4=cexd<CTRL>(w4,keep); w5=cexd<CTRL>(w5,keep); \
                             w6=cexd<CTRL>(w6,keep); w7=cexd<CTRL>(w7,keep); }
#define INL_J4A    { CE2A(w0,w4); CE2A(w1,w5); CE2A(w2,w6); CE2A(w3,w7); }
#define INL_J2A    { CE2A(w0,w2); CE2A(w1,w3); CE2A(w4,w6); CE2A(w5,w7); }
#define INL_J1A    { CE2A(w0,w1); CE2A(w2,w3); CE2A(w4,w5); CE2A(w6,w7); }
#define FOLD2(m1, m2, CTRL) { \
    unsigned q1_ = movdppu<CTRL>(m1), q2_ = movdppu<CTRL>(m2); \
    unsigned lo_ = umin_(m1, q1_); \
    m1 = umax_(m1, q1_); \
    m2 = umax_(lo_, umax_(m2, q2_)); }

__global__ __launch_bounds__(kBlock, 6)
void prl_user_kernel(const float* __restrict__ y_hat,
                     const float* __restrict__ y_true,
                     const float* __restrict__ rnd,
                     float* __restrict__ partials)
{
    const int lane = threadIdx.x & 63;
    const int wv   = threadIdx.x >> 6;
    const int wid  = (blockIdx.x * kBlock + threadIdx.x) >> 6;
    const int p    = lane & 7;           // physical lane within user
    const int g3   = lane >> 3;          // user (0..7) within wave

    // logical lane bits for map {1,2,4}->{1,2,7}: l = M^-1(p)
    const int l2 = (p >> 2) & 1;
    const int l0 = (p & 1) ^ l2;
    const int l1 = ((p >> 1) & 1) ^ l2;

    const unsigned SGN = 0x80000000u;
    const unsigned flip8  = l0 ? SGN : 0u;          // enter k=8 (dir l0)
    const unsigned flip16 = (l0 ^ l1) ? SGN : 0u;   // enter k=16 (dir l1)
    const unsigned flip32 = (l1 ^ l2) ? SGN : 0u;   // enter k=32 (dir l2)
    const unsigned unfl   = l2 ? SGN : 0u;          // back to true space
    const unsigned long long keep1 = __ballot(l0 == 0);  // logical j=8
    const unsigned long long keep2 = __ballot(l1 == 0);  // logical j=16

    const unsigned cb = 63u - ((unsigned)p << 3);   // 63 - item_idx base

    __shared__ __align__(16) float yh_tab[kWavesPerBlock][8][68];
    __shared__ float wsum[kWavesPerBlock];
    float* tg = &yh_tab[wv][g3][0];

    const int ub = wid * kUsersPerWave;
    #define ADDR(b_) (((ub + (b_) * 8) << 6) + (lane << 3))

    float acc = 0.0f;

    // proven R17 body as a value-taking lambda (reads occur at call sites,
    // which are always after the owning set's waitcnt + sched_barrier)
    auto body = [&](float4 ta, float4 tb, float4 ra, float4 rb,
                    float4 ha, float4 hb) -> float {
        *reinterpret_cast<float4*>(tg + (p << 3))     = ha;
        *reinterpret_cast<float4*>(tg + (p << 3) + 4) = hb;

        const unsigned kk0 = (__float_as_uint(ra.x) & ~63u) | cb;
        const unsigned kk1 = (__float_as_uint(ra.y) & ~63u) | (cb - 1u);
        const unsigned kk2 = (__float_as_uint(ra.z) & ~63u) | (cb - 2u);
        const unsigned kk3 = (__float_as_uint(ra.w) & ~63u) | (cb - 3u);
        const unsigned kk4 = (__float_as_uint(rb.x) & ~63u) | (cb - 4u);
        const unsigned kk5 = (__float_as_uint(rb.y) & ~63u) | (cb - 5u);
        const unsigned kk6 = (__float_as_uint(rb.z) & ~63u) | (cb - 6u);
        const unsigned kk7 = (__float_as_uint(rb.w) & ~63u) | (cb - 7u);

        float w0 = ta.x, w1 = ta.y, w2 = ta.z, w3 = ta.w;
        float w4 = tb.x, w5 = tb.y, w6 = tb.z, w7 = tb.w;
        CE2A(w0,w1); CE2D(w2,w3); CE2A(w4,w5); CE2D(w6,w7);   // k=2
        CE2A(w0,w2); CE2A(w1,w3); CE2D(w4,w6); CE2D(w5,w7);   // k=4 j=2
        CE2A(w0,w1); CE2A(w2,w3); CE2D(w4,w5); CE2D(w6,w7);   //     j=1
        FLIPALL(flip8);
        INL_J4A; INL_J2A; INL_J1A;                            // k=8
        FLIPALL(flip16);
        CEXALL(0xB1, keep1);                                  // k=16 j=8
        INL_J4A; INL_J2A; INL_J1A;
        FLIPALL(flip32);
        CEXALL(0x4E, keep2);                                  // k=32 j=16
        CEXALL(0xB1, keep1);                                  //      j=8
        INL_J4A; INL_J2A; INL_J1A;
        FLIPALL(unfl);
        const float s0 = fminf(w0, movdppf<0x141>(w0));
        const float s1 = fminf(w1, movdppf<0x141>(w1));
        const float s2 = fminf(w2, movdppf<0x141>(w2));
        const float s3 = fminf(w3, movdppf<0x141>(w3));
        const float s4 = fminf(w4, movdppf<0x141>(w4));
        const float s5 = fminf(w5, movdppf<0x141>(w5));
        const float s6 = fminf(w6, movdppf<0x141>(w6));
        const float s7 = fminf(w7, movdppf<0x141>(w7));
        float m = fmaxf(fmaxf(fmaxf(s0, s1), fmaxf(s2, s3)),
                        fmaxf(fmaxf(s4, s5), fmaxf(s6, s7)));
        m = fmaxf(m, movdppf<0xB1>(m));
        m = fmaxf(m, movdppf<0x4E>(m));
        m = fmaxf(m, movdppf<0x141>(m));
        const float a31 = m;                    // uniform within 8-lane user

        const bool p0m = ta.x > a31, p1m = ta.y > a31,
                   p2m = ta.z > a31, p3m = ta.w > a31,
                   p4m = tb.x > a31, p5m = tb.y > a31,
                   p6m = tb.z > a31, p7m = tb.w > a31;

        auto top2 = [&](unsigned k0, unsigned k1, unsigned k2, unsigned k3,
                        unsigned k4, unsigned k5, unsigned k6, unsigned k7,
                        unsigned& m1, unsigned& m2) {
            const unsigned h1 = umax_(k0,k1), q1 = umin_(k0,k1);
            const unsigned h2 = umax_(k2,k3), q2 = umin_(k2,k3);
            const unsigned h3 = umax_(k4,k5), q3 = umin_(k4,k5);
            const unsigned h4 = umax_(k6,k7), q4 = umin_(k6,k7);
            const unsigned ma = umax_(h1,h2);
            const unsigned sa = umax_(umin_(h1,h2), umax_(q1,q2));
            const unsigned mb = umax_(h3,h4);
            const unsigned sb = umax_(umin_(h3,h4), umax_(q3,q4));
            m1 = umax_(ma,mb);
            m2 = umax_(umin_(ma,mb), umax_(sa,sb));
            FOLD2(m1, m2, 0xB1);
            FOLD2(m1, m2, 0x4E);
            FOLD2(m1, m2, 0x141);
        };
        unsigned pm1, pm2, nm1, nm2;
        top2(p0m ? kk0 : 0u, p1m ? kk1 : 0u, p2m ? kk2 : 0u, p3m ? kk3 : 0u,
             p4m ? kk4 : 0u, p5m ? kk5 : 0u, p6m ? kk6 : 0u, p7m ? kk7 : 0u,
             pm1, pm2);
        top2(p0m ? 0u : kk0, p1m ? 0u : kk1, p2m ? 0u : kk2, p3m ? 0u : kk3,
             p4m ? 0u : kk4, p5m ? 0u : kk5, p6m ? 0u : kk6, p7m ? 0u : kk7,
             nm1, nm2);

        const float P0 = tg[(pm1 & 63u) ^ 63u];
        const float P1 = tg[(pm2 & 63u) ^ 63u];
        const float N0 = tg[(nm1 & 63u) ^ 63u];
        const float N1 = tg[(nm2 & 63u) ^ 63u];

        float s = 0.0f;
        s += fmaxf(kMargin - (P0 - N0), 0.0f);
        s += fmaxf(kMargin - (P0 - N1), 0.0f);
        s += fmaxf(kMargin - (P1 - N0), 0.0f);
        s += fmaxf(kMargin - (P1 - N1), 0.0f);
        return 0.25f * s;
    };

    // ---- fully unrolled 4-body double-buffered pipeline (sets A,B) ----
    // prologue: set A <- body 0
    float4 Ata = gload4(y_true + ADDR(0)), Atb = gload4(y_true + ADDR(0) + 4);
    float4 Ara = gload4(rnd    + ADDR(0)), Arb = gload4(rnd    + ADDR(0) + 4);
    float4 Aha = gload4(y_hat  + ADDR(0)), Ahb = gload4(y_hat  + ADDR(0) + 4);

    // body 0: issue set B <- body 1; wait for A; compute A
    float4 Bta = gload4(y_true + ADDR(1)), Btb = gload4(y_true + ADDR(1) + 4);
    float4 Bra = gload4(rnd    + ADDR(1)), Brb = gload4(rnd    + ADDR(1) + 4);
    float4 Bha = gload4(y_hat  + ADDR(1)), Bhb = gload4(y_hat  + ADDR(1) + 4);
    asm volatile("s_waitcnt vmcnt(6)" ::: "memory");
    __builtin_amdgcn_sched_barrier(0);
    acc += body(Ata, Atb, Ara, Arb, Aha, Ahb);

    // body 1: issue set A <- body 2; wait for B; compute B
    Ata = gload4(y_true + ADDR(2)); Atb = gload4(y_true + ADDR(2) + 4);
    Ara = gload4(rnd    + ADDR(2)); Arb = gload4(rnd    + ADDR(2) + 4);
    Aha = gload4(y_hat  + ADDR(2)); Ahb = gload4(y_hat  + ADDR(2) + 4);
    asm volatile("s_waitcnt vmcnt(6)" ::: "memory");
    __builtin_amdgcn_sched_barrier(0);
    acc += body(Bta, Btb, Bra, Brb, Bha, Bhb);

    // body 2: issue set B <- body 3; wait for A; compute A
    Bta = gload4(y_true + ADDR(3)); Btb = gload4(y_true + ADDR(3) + 4);
    Bra = gload4(rnd    + ADDR(3)); Brb = gload4(rnd    + ADDR(3) + 4);
    Bha = gload4(y_hat  + ADDR(3)); Bhb = gload4(y_hat  + ADDR(3) + 4);
    asm volatile("s_waitcnt vmcnt(6)" ::: "memory");
    __builtin_amdgcn_sched_barrier(0);
    acc += body(Ata, Atb, Ara, Arb, Aha, Ahb);

    // body 3: wait for B; compute B
    asm volatile("s_waitcnt vmcnt(0)" ::: "memory");
    __builtin_amdgcn_sched_barrier(0);
    acc += body(Bta, Btb, Bra, Brb, Bha, Bhb);
    #undef ADDR

    // acc uniform within each 8-lane user; sum the 8 group leaders
    float contrib = (p == 0) ? acc : 0.0f;
    contrib += __shfl_xor(contrib, 8);
    contrib += __shfl_xor(contrib, 16);
    contrib += __shfl_xor(contrib, 32);

    if (lane == 0) wsum[wv] = contrib;
    __syncthreads();
    if (threadIdx.x == 0) {
        float tsum = 0.0f;
        #pragma unroll
        for (int i = 0; i < kWavesPerBlock; ++i) tsum += wsum[i];
        partials[blockIdx.x] = tsum;
    }
}

__global__ void prl_reduce_kernel(const float* __restrict__ partials,
                                  float* __restrict__ out)
{
    float tv = 0.0f;
    for (int i = threadIdx.x; i < kGrid; i += 256) tv += partials[i];
    #pragma unroll
    for (int s = 32; s > 0; s >>= 1) tv += __shfl_xor(tv, s);
    __shared__ float ws[4];
    if ((threadIdx.x & 63) == 0) ws[threadIdx.x >> 6] = tv;
    __syncthreads();
    if (threadIdx.x == 0) {
        out[0] = (ws[0] + ws[1] + ws[2] + ws[3]) * (1.0f / (float)kUsers);
    }
}

extern "C" void kernel_launch(void* const* d_in, const int* in_sizes, int n_in,
                              void* d_out, int out_size, void* d_ws, size_t ws_size,
                              hipStream_t stream) {
    const float* y_hat  = (const float*)d_in[0];
    const float* y_true = (const float*)d_in[1];
    const float* rnd    = (const float*)d_in[2];
    // d_in[3] = user_idx: contiguous equal-size segments -> never read
    float* partials = (float*)d_ws;          // kGrid floats = 8 KiB scratch
    float* out      = (float*)d_out;

    hipLaunchKernelGGL(prl_user_kernel, dim3(kGrid), dim3(kBlock), 0, stream,
                       y_hat, y_true, rnd, partials);
    hipLaunchKernelGGL(prl_reduce_kernel, dim3(1), dim3(256), 0, stream,
                       partials, out);
}